// Round 6
// baseline (486.816 us; speedup 1.0000x reference)
//
#include <hip/hip_runtime.h>
#include <stdint.h>

#define ED   768
#define NH   12
#define HD   64
#define SEQ  4096
#define BSZ  2
#define BHT  (BSZ*NH)          // 24
#define MTOT (BSZ*SEQ)         // 8192

typedef short bf16x8  __attribute__((ext_vector_type(8)));   // 8 bf16 (4 VGPRs)
typedef float f32x4   __attribute__((ext_vector_type(4)));
typedef float f32x16  __attribute__((ext_vector_type(16)));
typedef unsigned int u32x4 __attribute__((ext_vector_type(4)));

#define LOG2E 1.44269504088896340736f
#define C2    (0.125f * LOG2E)   // folded into Q at projection time

// fp32 -> bf16 round-to-nearest-even
__device__ __forceinline__ unsigned short f2bf(float f) {
    union { float f; uint32_t u; } v; v.f = f;
    uint32_t u = v.u;
    u += 0x7fffu + ((u >> 16) & 1u);
    return (unsigned short)(u >> 16);
}

// pack two f32 -> one u32 holding 2 bf16 (lo = first arg)
__device__ __forceinline__ uint32_t cvtpk(float lo, float hi) {
    uint32_t r;
    asm("v_cvt_pk_bf16_f32 %0, %1, %2" : "=v"(r) : "v"(lo), "v"(hi));
    return r;
}

// async global->LDS, 16B/lane; lds dst = wave-uniform base, lands at base+lane*16
__device__ __forceinline__ void cp16(const unsigned short* g, unsigned short* l) {
    __builtin_amdgcn_global_load_lds(
        (const __attribute__((address_space(1))) unsigned int*)(const void*)g,
        (__attribute__((address_space(3))) unsigned int*)(void*)l,
        16, 0, 0);
}
// XOR-swizzle: LDS 16B-chunk slot c of row r holds global chunk c^(r&7).
// Staging: lane fetches global chunk (lane&7)^(lrow&7); reads use chunk^(row&7).

// ---------------------------------------------------------------------------
// Kernel 0: one-time fp32->bf16 convert. H,Wq|Wk|Wv -> d_out scratch (dead
// until out_gemm writes); Wo -> WoB in d_ws.
// ---------------------------------------------------------------------------
#define H_CHUNKS  (MTOT * ED / 4)            // 1572864 float4s
#define W_CHUNKS  (ED * ED / 4)              // 147456 per weight
#define CVT_TOTAL (H_CHUNKS + 4 * W_CHUNKS)  // 2162688 = 8448 * 256

__global__ __launch_bounds__(256) void convert_bf16(
    const float* __restrict__ H,  const float* __restrict__ Wq,
    const float* __restrict__ Wk, const float* __restrict__ Wv,
    const float* __restrict__ Wo, unsigned short* __restrict__ dst,
    unsigned short* __restrict__ WoB) {
    int i4 = blockIdx.x * 256 + threadIdx.x;
    float4 v;
    ushort4* optr;
    if (i4 < H_CHUNKS) { v = ((const float4*)H)[i4]; optr = (ushort4*)dst + i4; }
    else {
        int j = i4 - H_CHUNKS;
        if (j < 3 * W_CHUNKS) {
            if (j < W_CHUNKS)          v = ((const float4*)Wq)[j];
            else if (j < 2 * W_CHUNKS) v = ((const float4*)Wk)[j - W_CHUNKS];
            else                       v = ((const float4*)Wv)[j - 2 * W_CHUNKS];
            optr = (ushort4*)dst + i4;
        } else {
            v = ((const float4*)Wo)[j - 3 * W_CHUNKS];
            optr = (ushort4*)WoB + (j - 3 * W_CHUNKS);
        }
    }
    ushort4 o;
    o.x = f2bf(v.x); o.y = f2bf(v.y); o.z = f2bf(v.z); o.w = f2bf(v.w);
    *optr = o;
}

// ---------------------------------------------------------------------------
// Kernel 1: QKV projection, 128x128 tile, BK=64, global_load_lds + XOR swizzle.
// Q written pre-scaled by C2.  Q,K -> [b][h][s][d];  V -> [b][h][d][s].
// ---------------------------------------------------------------------------
__global__ __launch_bounds__(256) void qkv_gemm(
    const unsigned short* __restrict__ Hb,   // [8192][768] bf16
    const unsigned short* __restrict__ Wb,   // [2304][768] bf16 (Wq|Wk|Wv)
    unsigned short* __restrict__ qkv) {
    __shared__ __align__(16) unsigned short Ah[128 * 64];
    __shared__ __align__(16) unsigned short Bh[128 * 64];
    const int t = threadIdx.x, w = t >> 6, lane = t & 63;
    const int quad = lane >> 4, r16 = lane & 15;
    const int wm = w >> 1, wn = w & 1;
    const int m0 = blockIdx.y * 128, n0g = blockIdx.x * 128;
    const int wsel = n0g / ED, n0 = n0g % ED;
    const int lrow = lane >> 3;
    const int lchs = ((lane & 7) ^ (lrow & 7)) * 8;   // swizzled source chunk

    f32x4 acc[4][4] = {};
    for (int kt = 0; kt < ED / 64; ++kt) {
        const int k0 = kt * 64;
#pragma unroll
        for (int i = 0; i < 4; ++i) {
            int row = i * 32 + w * 8;
            cp16(&Hb[(size_t)(m0 + row + lrow) * ED + k0 + lchs], &Ah[row * 64]);
            cp16(&Wb[(size_t)(n0g + row + lrow) * ED + k0 + lchs], &Bh[row * 64]);
        }
        __syncthreads();
#pragma unroll
        for (int kk = 0; kk < 2; ++kk) {
            bf16x8 aF[4], bF[4];
#pragma unroll
            for (int mi = 0; mi < 4; ++mi) {
                int R = wm * 64 + mi * 16 + r16;
                aF[mi] = *(const bf16x8*)&Ah[R * 64 + (((kk * 4 + quad) ^ (r16 & 7)) * 8)];
            }
#pragma unroll
            for (int ni = 0; ni < 4; ++ni) {
                int R = wn * 64 + ni * 16 + r16;
                bF[ni] = *(const bf16x8*)&Bh[R * 64 + (((kk * 4 + quad) ^ (r16 & 7)) * 8)];
            }
            if (wsel == 2) {   // V: compute C^T so V^T stores stay coalesced
#pragma unroll
                for (int mi = 0; mi < 4; ++mi)
#pragma unroll
                    for (int ni = 0; ni < 4; ++ni)
                        acc[mi][ni] = __builtin_amdgcn_mfma_f32_16x16x32_bf16(
                            bF[ni], aF[mi], acc[mi][ni], 0, 0, 0);
            } else {
#pragma unroll
                for (int mi = 0; mi < 4; ++mi)
#pragma unroll
                    for (int ni = 0; ni < 4; ++ni)
                        acc[mi][ni] = __builtin_amdgcn_mfma_f32_16x16x32_bf16(
                            aF[mi], bF[ni], acc[mi][ni], 0, 0, 0);
            }
        }
        __syncthreads();
    }
    const size_t WSZ = (size_t)BHT * SEQ * HD;
    if (wsel == 2) {
#pragma unroll
        for (int mi = 0; mi < 4; ++mi)
#pragma unroll
            for (int ni = 0; ni < 4; ++ni)
#pragma unroll
                for (int r = 0; r < 4; ++r) {
                    int m  = m0 + wm * 64 + mi * 16 + r16;
                    int nn = n0 + wn * 64 + ni * 16 + quad * 4 + r;
                    int b = m >> 12, s = m & 4095;
                    int hh = nn >> 6, dd = nn & 63;
                    qkv[2 * WSZ + (((size_t)b * NH + hh) * HD + dd) * SEQ + s] =
                        f2bf(acc[mi][ni][r]);
                }
    } else {
        const float sc = (wsel == 0) ? C2 : 1.0f;
#pragma unroll
        for (int mi = 0; mi < 4; ++mi)
#pragma unroll
            for (int ni = 0; ni < 4; ++ni)
#pragma unroll
                for (int r = 0; r < 4; ++r) {
                    int m = m0 + wm * 64 + mi * 16 + quad * 4 + r;
                    int b = m >> 12, s = m & 4095;
                    int nn = n0 + wn * 64 + ni * 16 + r16;
                    int hh = nn >> 6, dd = nn & 63;
                    size_t off = (((size_t)b * NH + hh) * SEQ + s) * HD + dd;
                    qkv[(size_t)wsel * WSZ + off] = f2bf(acc[mi][ni][r] * sc);
                }
    }
}

// ---------------------------------------------------------------------------
// Kernel 2: flash attention, 32x32x16 MFMA, fixed-max softmax, Q pre-scaled.
// Round-6 (r3 sync structure — single __syncthreads per tile — kept intact):
//  - V read DIRECT from global (L2-resident 24MB): V^T rows are contiguous
//    exactly as PV B-fragments need; swizzle algebra cancels. Vtsm deleted
//    (LDS 40->24KB), 2 cp16 + 8 ds_read_b128 off the PV critical path.
//  - dual-accumulator chains: QK per st = sE(mask,k0,k2) + sO(k1,k3), depth
//    3 vs 5, merged in the exp2 add; PV oAcc split oA(kc0,1)/oB(kc2,3),
//    depth 2 vs 4, merged once at kernel end. Cuts ~400-500 cyc serial
//    latency per wave-tile (r5 lesson: stall is chain latency, not vmcnt).
// ---------------------------------------------------------------------------
__global__ __launch_bounds__(256) void flash_attn(
    const unsigned short* __restrict__ qkv, const float* __restrict__ mask,
    unsigned short* __restrict__ ctx) {
    __shared__ __align__(16) unsigned short Ksm[2 * 4096];   // [key][dim], swizzled, 16KB
    __shared__ __align__(16) unsigned short Mall[SEQ];       // log2-domain bf16 mask, 8KB
    const int t  = threadIdx.x;
    const int bh = blockIdx.y;
    const int b  = bh / NH;
    const int h  = bh % NH;
    const int qbase = blockIdx.x * 128;
    const size_t WSZ = (size_t)BHT * SEQ * HD;
    const unsigned short* Qp = qkv + (size_t)bh * SEQ * HD;
    const unsigned short* Kp = Qp + WSZ;
    const unsigned short* Vt = qkv + 2 * WSZ + (size_t)bh * HD * SEQ;
    const int w = t >> 6, lane = t & 63, n31 = lane & 31, hi = lane >> 5;
    const int lrow = lane >> 3;
    const int lchs = ((lane & 7) ^ (lrow & 7)) * 8;

    bf16x8 qF[4];
    {
        int qrow = qbase + w * 32 + n31;
#pragma unroll
        for (int kc = 0; kc < 4; ++kc)
            qF[kc] = *(const bf16x8*)&Qp[(size_t)qrow * HD + kc * 16 + hi * 8];
    }
    bf16x8 bOnes = {};
    if (hi == 0) bOnes[0] = (short)0x3F80;   // 1.0 at k==0
    bf16x8 aOnes;
#pragma unroll
    for (int i = 0; i < 8; ++i) aOnes[i] = (short)0x3F80;  // all-ones A fragment

    // one-time: whole mask row for this batch -> LDS, log2 domain, bf16
#pragma unroll
    for (int i = 0; i < 4; ++i) {
        float4 mv = ((const float4*)(mask + (size_t)b * SEQ))[i * 256 + t];
        ushort4 o;
        o.x = f2bf(LOG2E * mv.x); o.y = f2bf(LOG2E * mv.y);
        o.z = f2bf(LOG2E * mv.z); o.w = f2bf(LOG2E * mv.w);
        *(ushort4*)&Mall[(i * 256 + t) * 4] = o;
    }

    // per-lane V^T row pointers (contiguous fragment reads, no staging)
    const unsigned short* vR0 = Vt + (size_t)n31 * SEQ + hi * 8;
    const unsigned short* vR1 = Vt + (size_t)(32 + n31) * SEQ + hi * 8;

    // prologue: stage K(0) into buffer 0
    {
        int row0 = w * 16, row1 = w * 16 + 8;
        cp16(&Kp[(size_t)(row0 + lrow) * HD + lchs], &Ksm[row0 * 64]);
        cp16(&Kp[(size_t)(row1 + lrow) * HD + lchs], &Ksm[row1 * 64]);
    }
    __syncthreads();

    f32x16 oA[2] = {}, oB[2] = {};
    f32x16 lAcc = {};
    const f32x16 Z = {};
    const int sw = n31 & 7;                  // row-swizzle for K frag reads
    int cur = 0;

    for (int kt = 0; kt < SEQ / 64; ++kt) {
        // issue next K tile: flies during this tile's compute
        if (kt + 1 < SEQ / 64) {
            int row0 = w * 16, row1 = w * 16 + 8;
            int koff = (cur ^ 1) << 12;
            cp16(&Kp[(size_t)((kt + 1) * 64 + row0 + lrow) * HD + lchs], &Ksm[koff + row0 * 64]);
            cp16(&Kp[(size_t)((kt + 1) * 64 + row1 + lrow) * HD + lchs], &Ksm[koff + row1 * 64]);
        }

        // S^T = K Q^T (log2 domain) + mask via MFMA C-init; dual chains
        bf16x8 pF[4];
#pragma unroll
        for (int st = 0; st < 2; ++st) {
            bf16x8 am = {};
            {
                unsigned short mv = Mall[kt * 64 + st * 32 + n31];
                am[0] = (hi == 0) ? (short)mv : (short)0;
            }
            bf16x8 kF[4];
#pragma unroll
            for (int kc = 0; kc < 4; ++kc)
                kF[kc] = *(const bf16x8*)
                    &Ksm[(cur << 12) + (st * 32 + n31) * 64 + (((2 * kc + hi) ^ sw) * 8)];
            f32x16 sE = __builtin_amdgcn_mfma_f32_32x32x16_bf16(am, bOnes, Z, 0, 0, 0);
            __builtin_amdgcn_s_setprio(1);
            sE = __builtin_amdgcn_mfma_f32_32x32x16_bf16(kF[0], qF[0], sE, 0, 0, 0);
            f32x16 sO = __builtin_amdgcn_mfma_f32_32x32x16_bf16(kF[1], qF[1], Z, 0, 0, 0);
            sE = __builtin_amdgcn_mfma_f32_32x32x16_bf16(kF[2], qF[2], sE, 0, 0, 0);
            sO = __builtin_amdgcn_mfma_f32_32x32x16_bf16(kF[3], qF[3], sO, 0, 0, 0);
            __builtin_amdgcn_s_setprio(0);

            // exp2(sE+sO) + in-register transpose to PV B-fragments (T12)
            float p_[16];
#pragma unroll
            for (int r = 0; r < 16; ++r) p_[r] = __builtin_amdgcn_exp2f(sE[r] + sO[r]);
            uint32_t pw[8];
#pragma unroll
            for (int i = 0; i < 8; ++i)
                pw[i] = cvtpk(p_[2 * i], p_[2 * i + 1]);
#pragma unroll
            for (int hf = 0; hf < 2; ++hf) {
                auto r02 = __builtin_amdgcn_permlane32_swap(
                    pw[hf * 4 + 0], pw[hf * 4 + 2], false, false);
                auto r13 = __builtin_amdgcn_permlane32_swap(
                    pw[hf * 4 + 1], pw[hf * 4 + 3], false, false);
                union { u32x4 u; bf16x8 h; } f;
                f.u[0] = r02[0]; f.u[1] = r13[0]; f.u[2] = r02[1]; f.u[3] = r13[1];
                pF[st * 2 + hf] = f.h;
            }
        }

        // O^T += V^T P^T with V fragments direct from global (L2-hit);
        // split accumulators: oA gets kc0,1; oB gets kc2,3.
        __builtin_amdgcn_s_setprio(1);
#pragma unroll
        for (int kc = 0; kc < 4; ++kc) {
            lAcc = __builtin_amdgcn_mfma_f32_32x32x16_bf16(
                aOnes, pF[kc], lAcc, 0, 0, 0);
            bf16x8 v0 = *(const bf16x8*)&vR0[kt * 64 + kc * 16];
            bf16x8 v1 = *(const bf16x8*)&vR1[kt * 64 + kc * 16];
            if (kc < 2) {
                oA[0] = __builtin_amdgcn_mfma_f32_32x32x16_bf16(v0, pF[kc], oA[0], 0, 0, 0);
                oA[1] = __builtin_amdgcn_mfma_f32_32x32x16_bf16(v1, pF[kc], oA[1], 0, 0, 0);
            } else {
                oB[0] = __builtin_amdgcn_mfma_f32_32x32x16_bf16(v0, pF[kc], oB[0], 0, 0, 0);
                oB[1] = __builtin_amdgcn_mfma_f32_32x32x16_bf16(v1, pF[kc], oB[1], 0, 0, 0);
            }
        }
        __builtin_amdgcn_s_setprio(0);

        __syncthreads();   // drains K prefetch; K buffer flip safe
        cur ^= 1;
    }

    float inv = 1.0f / lAcc[0];   // all regs/halves hold the full row sum for q=n31
    int s = qbase + w * 32 + n31;
    unsigned short* obase = &ctx[((size_t)b * SEQ + s) * ED + h * HD];
#pragma unroll
    for (int dt = 0; dt < 2; ++dt) {
        f32x16 oSum = oA[dt] + oB[dt];
#pragma unroll
        for (int g = 0; g < 4; ++g) {
            ushort4 o;
            o.x = f2bf(oSum[4 * g + 0] * inv);
            o.y = f2bf(oSum[4 * g + 1] * inv);
            o.z = f2bf(oSum[4 * g + 2] * inv);
            o.w = f2bf(oSum[4 * g + 3] * inv);
            *(ushort4*)&obase[dt * 32 + hi * 4 + 8 * g] = o;
        }
    }
}

// ---------------------------------------------------------------------------
// Kernel 3: output projection, 128x128 tile m97-style.
// out[m][n] = sum_k ctx[m][k]*Wo[n][k] + bo[n], fp32 output.
// ---------------------------------------------------------------------------
__global__ __launch_bounds__(256) void out_gemm(
    const unsigned short* __restrict__ Ab,   // ctx bf16 [8192][768]
    const unsigned short* __restrict__ Wob,  // [768][768] bf16
    const float* __restrict__ bo, float* __restrict__ out) {
    __shared__ __align__(16) unsigned short Ah[128 * 64];
    __shared__ __align__(16) unsigned short Bh[128 * 64];
    const int t = threadIdx.x, w = t >> 6, lane = t & 63;
    const int quad = lane >> 4, r16 = lane & 15;
    const int wm = w >> 1, wn = w & 1;
    const int m0 = blockIdx.y * 128, n0 = blockIdx.x * 128;
    const int lrow = lane >> 3;
    const int lchs = ((lane & 7) ^ (lrow & 7)) * 8;

    f32x4 acc[4][4] = {};
    for (int kt = 0; kt < ED / 64; ++kt) {
        const int k0 = kt * 64;
#pragma unroll
        for (int i = 0; i < 4; ++i) {
            int row = i * 32 + w * 8;
            cp16(&Ab[(size_t)(m0 + row + lrow) * ED + k0 + lchs], &Ah[row * 64]);
            cp16(&Wob[(size_t)(n0 + row + lrow) * ED + k0 + lchs], &Bh[row * 64]);
        }
        __syncthreads();
#pragma unroll
        for (int kk = 0; kk < 2; ++kk) {
            bf16x8 aF[4], bF[4];
#pragma unroll
            for (int mi = 0; mi < 4; ++mi) {
                int R = wm * 64 + mi * 16 + r16;
                aF[mi] = *(const bf16x8*)&Ah[R * 64 + (((kk * 4 + quad) ^ (r16 & 7)) * 8)];
            }
#pragma unroll
            for (int ni = 0; ni < 4; ++ni) {
                int R = wn * 64 + ni * 16 + r16;
                bF[ni] = *(const bf16x8*)&Bh[R * 64 + (((kk * 4 + quad) ^ (r16 & 7)) * 8)];
            }
#pragma unroll
            for (int mi = 0; mi < 4; ++mi)
#pragma unroll
                for (int ni = 0; ni < 4; ++ni)
                    acc[mi][ni] = __builtin_amdgcn_mfma_f32_16x16x32_bf16(
                        aF[mi], bF[ni], acc[mi][ni], 0, 0, 0);
        }
        __syncthreads();
    }
    float bov[4];
#pragma unroll
    for (int ni = 0; ni < 4; ++ni) bov[ni] = bo[n0 + wn * 64 + ni * 16 + r16];
#pragma unroll
    for (int mi = 0; mi < 4; ++mi)
#pragma unroll
        for (int ni = 0; ni < 4; ++ni)
#pragma unroll
            for (int r = 0; r < 4; ++r) {
                int m = m0 + wm * 64 + mi * 16 + quad * 4 + r;
                int n = n0 + wn * 64 + ni * 16 + r16;
                out[(size_t)m * ED + n] = acc[mi][ni][r] + bov[ni];
            }
}

// ---------------------------------------------------------------------------
extern "C" void kernel_launch(void* const* d_in, const int* in_sizes, int n_in,
                              void* d_out, int out_size, void* d_ws, size_t ws_size,
                              hipStream_t stream) {
    const float* H    = (const float*)d_in[0];
    const float* mask = (const float*)d_in[1];
    const float* Wq   = (const float*)d_in[2];
    const float* Wk   = (const float*)d_in[3];
    const float* Wv   = (const float*)d_in[4];
    const float* Wo   = (const float*)d_in[5];
    const float* bo   = (const float*)d_in[6];
    unsigned short* ws = (unsigned short*)d_ws;
    const size_t WSZ = (size_t)BHT * SEQ * HD;
    unsigned short* qkv = ws;                           // 3*WSZ bf16
    unsigned short* ctx = ws + 3 * WSZ;                 // [8192][768] bf16
    unsigned short* WoB = ctx + (size_t)MTOT * ED;      // [768][768] bf16
    float* out = (float*)d_out;
    // d_out doubles as scratch for bf16 H and Wqkv until out_gemm overwrites it
    unsigned short* Hb = (unsigned short*)d_out;        // 6291456 elems
    unsigned short* Wb = Hb + (size_t)MTOT * ED;        // 1769472 elems

    convert_bf16<<<CVT_TOTAL / 256, 256, 0, stream>>>(H, Wq, Wk, Wv, Wo, Hb, WoB);
    qkv_gemm<<<dim3(3 * ED / 128, MTOT / 128), 256, 0, stream>>>(Hb, Wb, qkv);
    flash_attn<<<dim3(SEQ / 128, BHT), 256, 0, stream>>>(qkv, mask, ctx);
    out_gemm<<<dim3(ED / 128, MTOT / 128), 256, 0, stream>>>(ctx, WoB, bo, out);
}

// Round 7
// 320.409 us; speedup vs baseline: 1.5194x; 1.5194x over previous
//
#include <hip/hip_runtime.h>
#include <stdint.h>

#define ED   768
#define NH   12
#define HD   64
#define SEQ  4096
#define BSZ  2
#define BHT  (BSZ*NH)          // 24
#define MTOT (BSZ*SEQ)         // 8192

typedef short bf16x8  __attribute__((ext_vector_type(8)));   // 8 bf16 (4 VGPRs)
typedef float f32x4   __attribute__((ext_vector_type(4)));
typedef float f32x16  __attribute__((ext_vector_type(16)));
typedef unsigned int u32x4 __attribute__((ext_vector_type(4)));

#define LOG2E 1.44269504088896340736f
#define C2    (0.125f * LOG2E)   // folded into Q at projection time

// fp32 -> bf16 round-to-nearest-even
__device__ __forceinline__ unsigned short f2bf(float f) {
    union { float f; uint32_t u; } v; v.f = f;
    uint32_t u = v.u;
    u += 0x7fffu + ((u >> 16) & 1u);
    return (unsigned short)(u >> 16);
}

// pack two f32 -> one u32 holding 2 bf16 (lo = first arg)
__device__ __forceinline__ uint32_t cvtpk(float lo, float hi) {
    uint32_t r;
    asm("v_cvt_pk_bf16_f32 %0, %1, %2" : "=v"(r) : "v"(lo), "v"(hi));
    return r;
}

// async global->LDS, 16B/lane; lds dst = wave-uniform base, lands at base+lane*16
__device__ __forceinline__ void cp16(const unsigned short* g, unsigned short* l) {
    __builtin_amdgcn_global_load_lds(
        (const __attribute__((address_space(1))) unsigned int*)(const void*)g,
        (__attribute__((address_space(3))) unsigned int*)(void*)l,
        16, 0, 0);
}
// XOR-swizzle: LDS 16B-chunk slot c of row r holds global chunk c^(r&7).
// Staging: lane fetches global chunk (lane&7)^(lrow&7); reads use chunk^(row&7).

// ---------------------------------------------------------------------------
// Kernel 0: one-time fp32->bf16 convert. H,Wq|Wk|Wv -> d_out scratch (dead
// until out_gemm writes); Wo -> WoB in d_ws.
// ---------------------------------------------------------------------------
#define H_CHUNKS  (MTOT * ED / 4)            // 1572864 float4s
#define W_CHUNKS  (ED * ED / 4)              // 147456 per weight
#define CVT_TOTAL (H_CHUNKS + 4 * W_CHUNKS)  // 2162688 = 8448 * 256

__global__ __launch_bounds__(256) void convert_bf16(
    const float* __restrict__ H,  const float* __restrict__ Wq,
    const float* __restrict__ Wk, const float* __restrict__ Wv,
    const float* __restrict__ Wo, unsigned short* __restrict__ dst,
    unsigned short* __restrict__ WoB) {
    int i4 = blockIdx.x * 256 + threadIdx.x;
    float4 v;
    ushort4* optr;
    if (i4 < H_CHUNKS) { v = ((const float4*)H)[i4]; optr = (ushort4*)dst + i4; }
    else {
        int j = i4 - H_CHUNKS;
        if (j < 3 * W_CHUNKS) {
            if (j < W_CHUNKS)          v = ((const float4*)Wq)[j];
            else if (j < 2 * W_CHUNKS) v = ((const float4*)Wk)[j - W_CHUNKS];
            else                       v = ((const float4*)Wv)[j - 2 * W_CHUNKS];
            optr = (ushort4*)dst + i4;
        } else {
            v = ((const float4*)Wo)[j - 3 * W_CHUNKS];
            optr = (ushort4*)WoB + (j - 3 * W_CHUNKS);
        }
    }
    ushort4 o;
    o.x = f2bf(v.x); o.y = f2bf(v.y); o.z = f2bf(v.z); o.w = f2bf(v.w);
    *optr = o;
}

// ---------------------------------------------------------------------------
// Kernel 1: QKV projection, 128x128 tile, BK=64, global_load_lds + XOR swizzle.
// Q written pre-scaled by C2.  Q,K -> [b][h][s][d];  V -> [b][h][d][s].
// ---------------------------------------------------------------------------
__global__ __launch_bounds__(256) void qkv_gemm(
    const unsigned short* __restrict__ Hb,   // [8192][768] bf16
    const unsigned short* __restrict__ Wb,   // [2304][768] bf16 (Wq|Wk|Wv)
    unsigned short* __restrict__ qkv) {
    __shared__ __align__(16) unsigned short Ah[128 * 64];
    __shared__ __align__(16) unsigned short Bh[128 * 64];
    const int t = threadIdx.x, w = t >> 6, lane = t & 63;
    const int quad = lane >> 4, r16 = lane & 15;
    const int wm = w >> 1, wn = w & 1;
    const int m0 = blockIdx.y * 128, n0g = blockIdx.x * 128;
    const int wsel = n0g / ED, n0 = n0g % ED;
    const int lrow = lane >> 3;
    const int lchs = ((lane & 7) ^ (lrow & 7)) * 8;   // swizzled source chunk

    f32x4 acc[4][4] = {};
    for (int kt = 0; kt < ED / 64; ++kt) {
        const int k0 = kt * 64;
#pragma unroll
        for (int i = 0; i < 4; ++i) {
            int row = i * 32 + w * 8;
            cp16(&Hb[(size_t)(m0 + row + lrow) * ED + k0 + lchs], &Ah[row * 64]);
            cp16(&Wb[(size_t)(n0g + row + lrow) * ED + k0 + lchs], &Bh[row * 64]);
        }
        __syncthreads();
#pragma unroll
        for (int kk = 0; kk < 2; ++kk) {
            bf16x8 aF[4], bF[4];
#pragma unroll
            for (int mi = 0; mi < 4; ++mi) {
                int R = wm * 64 + mi * 16 + r16;
                aF[mi] = *(const bf16x8*)&Ah[R * 64 + (((kk * 4 + quad) ^ (r16 & 7)) * 8)];
            }
#pragma unroll
            for (int ni = 0; ni < 4; ++ni) {
                int R = wn * 64 + ni * 16 + r16;
                bF[ni] = *(const bf16x8*)&Bh[R * 64 + (((kk * 4 + quad) ^ (r16 & 7)) * 8)];
            }
            if (wsel == 2) {   // V: compute C^T so V^T stores stay coalesced
#pragma unroll
                for (int mi = 0; mi < 4; ++mi)
#pragma unroll
                    for (int ni = 0; ni < 4; ++ni)
                        acc[mi][ni] = __builtin_amdgcn_mfma_f32_16x16x32_bf16(
                            bF[ni], aF[mi], acc[mi][ni], 0, 0, 0);
            } else {
#pragma unroll
                for (int mi = 0; mi < 4; ++mi)
#pragma unroll
                    for (int ni = 0; ni < 4; ++ni)
                        acc[mi][ni] = __builtin_amdgcn_mfma_f32_16x16x32_bf16(
                            aF[mi], bF[ni], acc[mi][ni], 0, 0, 0);
            }
        }
        __syncthreads();
    }
    const size_t WSZ = (size_t)BHT * SEQ * HD;
    if (wsel == 2) {
#pragma unroll
        for (int mi = 0; mi < 4; ++mi)
#pragma unroll
            for (int ni = 0; ni < 4; ++ni)
#pragma unroll
                for (int r = 0; r < 4; ++r) {
                    int m  = m0 + wm * 64 + mi * 16 + r16;
                    int nn = n0 + wn * 64 + ni * 16 + quad * 4 + r;
                    int b = m >> 12, s = m & 4095;
                    int hh = nn >> 6, dd = nn & 63;
                    qkv[2 * WSZ + (((size_t)b * NH + hh) * HD + dd) * SEQ + s] =
                        f2bf(acc[mi][ni][r]);
                }
    } else {
        const float sc = (wsel == 0) ? C2 : 1.0f;
#pragma unroll
        for (int mi = 0; mi < 4; ++mi)
#pragma unroll
            for (int ni = 0; ni < 4; ++ni)
#pragma unroll
                for (int r = 0; r < 4; ++r) {
                    int m = m0 + wm * 64 + mi * 16 + quad * 4 + r;
                    int b = m >> 12, s = m & 4095;
                    int nn = n0 + wn * 64 + ni * 16 + r16;
                    int hh = nn >> 6, dd = nn & 63;
                    size_t off = (((size_t)b * NH + hh) * SEQ + s) * HD + dd;
                    qkv[(size_t)wsel * WSZ + off] = f2bf(acc[mi][ni][r] * sc);
                }
    }
}

// ---------------------------------------------------------------------------
// Kernel 2: flash attention, 32x32x16 MFMA, fixed-max softmax, Q pre-scaled.
// Round-7 = r3 verified dataflow (K+V staged together, one barrier/tile,
// LDS 40KB, V via LDS — r6's V-direct was uncoalesced, reverted) + register-
// pure ILP changes:
//  - FOUR independent QK chains: sE0(mask,k0,k2), sO0(k1,k3), sE1, sO1 —
//    10 MFMAs in one setprio bracket, max dep depth 3 (was 2 serial
//    brackets of depth 5). Merge in p = exp2(sE+sO).
//  - mask register prefetch: next tile's 2 Mall ushorts loaded during the
//    current tile (the ds_read was gating the sE chain head).
//  - __launch_bounds__(256,3): pin VGPR <=170 (grid caps at 3 blocks/CU;
//    4 live f32x16 chains push register pressure).
// ---------------------------------------------------------------------------
__global__ __launch_bounds__(256, 3) void flash_attn(
    const unsigned short* __restrict__ qkv, const float* __restrict__ mask,
    unsigned short* __restrict__ ctx) {
    __shared__ __align__(16) unsigned short Ksm[2][64 * 64];   // [key][dim], swizzled
    __shared__ __align__(16) unsigned short Vtsm[2][64 * 64];  // [dim][key], swizzled
    __shared__ __align__(16) unsigned short Mall[SEQ];         // log2-domain bf16 mask
    const int t  = threadIdx.x;
    const int bh = blockIdx.y;
    const int b  = bh / NH;
    const int h  = bh % NH;
    const int qbase = blockIdx.x * 128;
    const size_t WSZ = (size_t)BHT * SEQ * HD;
    const unsigned short* Qp = qkv + (size_t)bh * SEQ * HD;
    const unsigned short* Kp = Qp + WSZ;
    const unsigned short* Vt = qkv + 2 * WSZ + (size_t)bh * HD * SEQ;
    const int w = t >> 6, lane = t & 63, n31 = lane & 31, hi = lane >> 5;
    const int lrow = lane >> 3;
    const int lchs = ((lane & 7) ^ (lrow & 7)) * 8;

    bf16x8 qF[4];
    {
        int qrow = qbase + w * 32 + n31;
#pragma unroll
        for (int kc = 0; kc < 4; ++kc)
            qF[kc] = *(const bf16x8*)&Qp[(size_t)qrow * HD + kc * 16 + hi * 8];
    }
    bf16x8 bOnes = {};
    if (hi == 0) bOnes[0] = (short)0x3F80;   // 1.0 at k==0
    bf16x8 aOnes;
#pragma unroll
    for (int i = 0; i < 8; ++i) aOnes[i] = (short)0x3F80;  // all-ones A fragment

    // one-time: whole mask row for this batch -> LDS, log2 domain, bf16
#pragma unroll
    for (int i = 0; i < 4; ++i) {
        float4 mv = ((const float4*)(mask + (size_t)b * SEQ))[i * 256 + t];
        ushort4 o;
        o.x = f2bf(LOG2E * mv.x); o.y = f2bf(LOG2E * mv.y);
        o.z = f2bf(LOG2E * mv.z); o.w = f2bf(LOG2E * mv.w);
        *(ushort4*)&Mall[(i * 256 + t) * 4] = o;
    }

    // prologue: stage tile 0 into buffer 0
#pragma unroll
    for (int i = 0; i < 2; ++i) {
        int row = w * 16 + i * 8;
        cp16(&Kp[(size_t)(row + lrow) * HD + lchs], &Ksm[0][row * 64]);
        cp16(&Vt[(size_t)(row + lrow) * SEQ + lchs], &Vtsm[0][row * 64]);
    }
    __syncthreads();

    f32x16 oAcc[2] = {};
    f32x16 lAcc = {};
    const f32x16 Z = {};
    const int sw = n31 & 7;                  // row-swizzle for frag reads
    int cur = 0;
    // mask regs for tile 0 (Mall valid after the barrier above)
    unsigned short mC0 = Mall[n31], mC1 = Mall[32 + n31];

    for (int kt = 0; kt < SEQ / 64; ++kt) {
        // issue next-tile loads first: they fly during this tile's compute
        if (kt + 1 < SEQ / 64) {
#pragma unroll
            for (int i = 0; i < 2; ++i) {
                int row = w * 16 + i * 8;
                cp16(&Kp[(size_t)((kt + 1) * 64 + row + lrow) * HD + lchs],
                     &Ksm[cur ^ 1][row * 64]);
                cp16(&Vt[(size_t)(row + lrow) * SEQ + (kt + 1) * 64 + lchs],
                     &Vtsm[cur ^ 1][row * 64]);
            }
        }

        // S^T = K Q^T (log2 domain) + mask via MFMA C-init.
        // Four independent chains (sE0,sO0,sE1,sO1), depth <= 3.
        bf16x8 am0 = {}, am1 = {};
        if (hi == 0) { am0[0] = (short)mC0; am1[0] = (short)mC1; }
        // prefetch next tile's mask (off the chain head next iter)
        if (kt + 1 < SEQ / 64) {
            mC0 = Mall[(kt + 1) * 64 + n31];
            mC1 = Mall[(kt + 1) * 64 + 32 + n31];
        }
        bf16x8 kF0[4], kF1[4];
#pragma unroll
        for (int kc = 0; kc < 4; ++kc) {
            kF0[kc] = *(const bf16x8*)
                &Ksm[cur][n31 * 64 + (((2 * kc + hi) ^ sw) * 8)];
            kF1[kc] = *(const bf16x8*)
                &Ksm[cur][(32 + n31) * 64 + (((2 * kc + hi) ^ sw) * 8)];
        }
        f32x16 sE0 = __builtin_amdgcn_mfma_f32_32x32x16_bf16(am0, bOnes, Z, 0, 0, 0);
        f32x16 sE1 = __builtin_amdgcn_mfma_f32_32x32x16_bf16(am1, bOnes, Z, 0, 0, 0);
        __builtin_amdgcn_s_setprio(1);
        sE0 = __builtin_amdgcn_mfma_f32_32x32x16_bf16(kF0[0], qF[0], sE0, 0, 0, 0);
        f32x16 sO0 = __builtin_amdgcn_mfma_f32_32x32x16_bf16(kF0[1], qF[1], Z, 0, 0, 0);
        sE1 = __builtin_amdgcn_mfma_f32_32x32x16_bf16(kF1[0], qF[0], sE1, 0, 0, 0);
        f32x16 sO1 = __builtin_amdgcn_mfma_f32_32x32x16_bf16(kF1[1], qF[1], Z, 0, 0, 0);
        sE0 = __builtin_amdgcn_mfma_f32_32x32x16_bf16(kF0[2], qF[2], sE0, 0, 0, 0);
        sO0 = __builtin_amdgcn_mfma_f32_32x32x16_bf16(kF0[3], qF[3], sO0, 0, 0, 0);
        sE1 = __builtin_amdgcn_mfma_f32_32x32x16_bf16(kF1[2], qF[2], sE1, 0, 0, 0);
        sO1 = __builtin_amdgcn_mfma_f32_32x32x16_bf16(kF1[3], qF[3], sO1, 0, 0, 0);
        __builtin_amdgcn_s_setprio(0);

        // exp2(sE+sO) + in-register transpose to PV B-fragments (T12).
        // p[st][r] = P[q=n31][key = st*32 + (r&3)+8*(r>>2)+4*hi].
        bf16x8 pF[4];
#pragma unroll
        for (int st = 0; st < 2; ++st) {
            float p_[16];
#pragma unroll
            for (int r = 0; r < 16; ++r)
                p_[r] = __builtin_amdgcn_exp2f(st ? (sE1[r] + sO1[r])
                                                  : (sE0[r] + sO0[r]));
            uint32_t pw[8];
#pragma unroll
            for (int i = 0; i < 8; ++i)
                pw[i] = cvtpk(p_[2 * i], p_[2 * i + 1]);
#pragma unroll
            for (int hf = 0; hf < 2; ++hf) {
                auto r02 = __builtin_amdgcn_permlane32_swap(
                    pw[hf * 4 + 0], pw[hf * 4 + 2], false, false);
                auto r13 = __builtin_amdgcn_permlane32_swap(
                    pw[hf * 4 + 1], pw[hf * 4 + 3], false, false);
                union { u32x4 u; bf16x8 h; } f;
                f.u[0] = r02[0]; f.u[1] = r13[0]; f.u[2] = r02[1]; f.u[3] = r13[1];
                pF[st * 2 + hf] = f.h;
            }
        }

        // O^T += V^T P^T ; denominator via MFMA on the same fragments
        __builtin_amdgcn_s_setprio(1);
#pragma unroll
        for (int kc = 0; kc < 4; ++kc) {
            lAcc = __builtin_amdgcn_mfma_f32_32x32x16_bf16(
                aOnes, pF[kc], lAcc, 0, 0, 0);
#pragma unroll
            for (int dt = 0; dt < 2; ++dt) {
                bf16x8 vF = *(const bf16x8*)
                    &Vtsm[cur][(dt * 32 + n31) * 64 + (((2 * kc + hi) ^ sw) * 8)];
                oAcc[dt] = __builtin_amdgcn_mfma_f32_32x32x16_bf16(vF, pF[kc], oAcc[dt], 0, 0, 0);
            }
        }
        __builtin_amdgcn_s_setprio(0);

        __syncthreads();   // drains vmcnt: next tile staged; buffer flip safe
        cur ^= 1;
    }
    float inv = 1.0f / lAcc[0];   // all regs/halves hold the full row sum for q=n31
    int s = qbase + w * 32 + n31;
    unsigned short* obase = &ctx[((size_t)b * SEQ + s) * ED + h * HD];
#pragma unroll
    for (int dt = 0; dt < 2; ++dt)
#pragma unroll
        for (int g = 0; g < 4; ++g) {
            ushort4 o;
            o.x = f2bf(oAcc[dt][4 * g + 0] * inv);
            o.y = f2bf(oAcc[dt][4 * g + 1] * inv);
            o.z = f2bf(oAcc[dt][4 * g + 2] * inv);
            o.w = f2bf(oAcc[dt][4 * g + 3] * inv);
            *(ushort4*)&obase[dt * 32 + hi * 4 + 8 * g] = o;
        }
}

// ---------------------------------------------------------------------------
// Kernel 3: output projection, 128x128 tile m97-style.
// out[m][n] = sum_k ctx[m][k]*Wo[n][k] + bo[n], fp32 output.
// ---------------------------------------------------------------------------
__global__ __launch_bounds__(256) void out_gemm(
    const unsigned short* __restrict__ Ab,   // ctx bf16 [8192][768]
    const unsigned short* __restrict__ Wob,  // [768][768] bf16
    const float* __restrict__ bo, float* __restrict__ out) {
    __shared__ __align__(16) unsigned short Ah[128 * 64];
    __shared__ __align__(16) unsigned short Bh[128 * 64];
    const int t = threadIdx.x, w = t >> 6, lane = t & 63;
    const int quad = lane >> 4, r16 = lane & 15;
    const int wm = w >> 1, wn = w & 1;
    const int m0 = blockIdx.y * 128, n0 = blockIdx.x * 128;
    const int lrow = lane >> 3;
    const int lchs = ((lane & 7) ^ (lrow & 7)) * 8;

    f32x4 acc[4][4] = {};
    for (int kt = 0; kt < ED / 64; ++kt) {
        const int k0 = kt * 64;
#pragma unroll
        for (int i = 0; i < 4; ++i) {
            int row = i * 32 + w * 8;
            cp16(&Ab[(size_t)(m0 + row + lrow) * ED + k0 + lchs], &Ah[row * 64]);
            cp16(&Wob[(size_t)(n0 + row + lrow) * ED + k0 + lchs], &Bh[row * 64]);
        }
        __syncthreads();
#pragma unroll
        for (int kk = 0; kk < 2; ++kk) {
            bf16x8 aF[4], bF[4];
#pragma unroll
            for (int mi = 0; mi < 4; ++mi) {
                int R = wm * 64 + mi * 16 + r16;
                aF[mi] = *(const bf16x8*)&Ah[R * 64 + (((kk * 4 + quad) ^ (r16 & 7)) * 8)];
            }
#pragma unroll
            for (int ni = 0; ni < 4; ++ni) {
                int R = wn * 64 + ni * 16 + r16;
                bF[ni] = *(const bf16x8*)&Bh[R * 64 + (((kk * 4 + quad) ^ (r16 & 7)) * 8)];
            }
#pragma unroll
            for (int mi = 0; mi < 4; ++mi)
#pragma unroll
                for (int ni = 0; ni < 4; ++ni)
                    acc[mi][ni] = __builtin_amdgcn_mfma_f32_16x16x32_bf16(
                        aF[mi], bF[ni], acc[mi][ni], 0, 0, 0);
        }
        __syncthreads();
    }
    float bov[4];
#pragma unroll
    for (int ni = 0; ni < 4; ++ni) bov[ni] = bo[n0 + wn * 64 + ni * 16 + r16];
#pragma unroll
    for (int mi = 0; mi < 4; ++mi)
#pragma unroll
        for (int ni = 0; ni < 4; ++ni)
#pragma unroll
            for (int r = 0; r < 4; ++r) {
                int m = m0 + wm * 64 + mi * 16 + quad * 4 + r;
                int n = n0 + wn * 64 + ni * 16 + r16;
                out[(size_t)m * ED + n] = acc[mi][ni][r] + bov[ni];
            }
}

// ---------------------------------------------------------------------------
extern "C" void kernel_launch(void* const* d_in, const int* in_sizes, int n_in,
                              void* d_out, int out_size, void* d_ws, size_t ws_size,
                              hipStream_t stream) {
    const float* H    = (const float*)d_in[0];
    const float* mask = (const float*)d_in[1];
    const float* Wq   = (const float*)d_in[2];
    const float* Wk   = (const float*)d_in[3];
    const float* Wv   = (const float*)d_in[4];
    const float* Wo   = (const float*)d_in[5];
    const float* bo   = (const float*)d_in[6];
    unsigned short* ws = (unsigned short*)d_ws;
    const size_t WSZ = (size_t)BHT * SEQ * HD;
    unsigned short* qkv = ws;                           // 3*WSZ bf16
    unsigned short* ctx = ws + 3 * WSZ;                 // [8192][768] bf16
    unsigned short* WoB = ctx + (size_t)MTOT * ED;      // [768][768] bf16
    float* out = (float*)d_out;
    // d_out doubles as scratch for bf16 H and Wqkv until out_gemm overwrites it
    unsigned short* Hb = (unsigned short*)d_out;        // 6291456 elems
    unsigned short* Wb = Hb + (size_t)MTOT * ED;        // 1769472 elems

    convert_bf16<<<CVT_TOTAL / 256, 256, 0, stream>>>(H, Wq, Wk, Wv, Wo, Hb, WoB);
    qkv_gemm<<<dim3(3 * ED / 128, MTOT / 128), 256, 0, stream>>>(Hb, Wb, qkv);
    flash_attn<<<dim3(SEQ / 128, BHT), 256, 0, stream>>>(qkv, mask, ctx);
    out_gemm<<<dim3(ED / 128, MTOT / 128), 256, 0, stream>>>(ctx, WoB, bo, out);
}

// Round 8
// 291.301 us; speedup vs baseline: 1.6712x; 1.0999x over previous
//
#include <hip/hip_runtime.h>
#include <stdint.h>

#define ED   768
#define NH   12
#define HD   64
#define SEQ  4096
#define BSZ  2
#define BHT  (BSZ*NH)          // 24
#define MTOT (BSZ*SEQ)         // 8192

typedef short bf16x8  __attribute__((ext_vector_type(8)));   // 8 bf16 (4 VGPRs)
typedef float f32x4   __attribute__((ext_vector_type(4)));
typedef float f32x16  __attribute__((ext_vector_type(16)));
typedef unsigned int u32x4 __attribute__((ext_vector_type(4)));

#define LOG2E 1.44269504088896340736f
#define C2    (0.125f * LOG2E)   // folded into Q at projection time

// fp32 -> bf16 round-to-nearest-even
__device__ __forceinline__ unsigned short f2bf(float f) {
    union { float f; uint32_t u; } v; v.f = f;
    uint32_t u = v.u;
    u += 0x7fffu + ((u >> 16) & 1u);
    return (unsigned short)(u >> 16);
}

// pack two f32 -> one u32 holding 2 bf16 (lo = first arg)
__device__ __forceinline__ uint32_t cvtpk(float lo, float hi) {
    uint32_t r;
    asm("v_cvt_pk_bf16_f32 %0, %1, %2" : "=v"(r) : "v"(lo), "v"(hi));
    return r;
}

// async global->LDS, 16B/lane; lds dst = wave-uniform base, lands at base+lane*16
__device__ __forceinline__ void cp16(const unsigned short* g, unsigned short* l) {
    __builtin_amdgcn_global_load_lds(
        (const __attribute__((address_space(1))) unsigned int*)(const void*)g,
        (__attribute__((address_space(3))) unsigned int*)(void*)l,
        16, 0, 0);
}
// XOR-swizzle: LDS 16B-chunk slot c of row r holds global chunk c^(r&7).
// Staging: lane fetches global chunk (lane&7)^(lrow&7); reads use chunk^(row&7).

// ---------------------------------------------------------------------------
// Kernel 0: one-time fp32->bf16 convert. H,Wq|Wk|Wv -> d_out scratch (dead
// until out_gemm writes); Wo -> WoB in d_ws.
// ---------------------------------------------------------------------------
#define H_CHUNKS  (MTOT * ED / 4)            // 1572864 float4s
#define W_CHUNKS  (ED * ED / 4)              // 147456 per weight
#define CVT_TOTAL (H_CHUNKS + 4 * W_CHUNKS)  // 2162688 = 8448 * 256

__global__ __launch_bounds__(256) void convert_bf16(
    const float* __restrict__ H,  const float* __restrict__ Wq,
    const float* __restrict__ Wk, const float* __restrict__ Wv,
    const float* __restrict__ Wo, unsigned short* __restrict__ dst,
    unsigned short* __restrict__ WoB) {
    int i4 = blockIdx.x * 256 + threadIdx.x;
    float4 v;
    ushort4* optr;
    if (i4 < H_CHUNKS) { v = ((const float4*)H)[i4]; optr = (ushort4*)dst + i4; }
    else {
        int j = i4 - H_CHUNKS;
        if (j < 3 * W_CHUNKS) {
            if (j < W_CHUNKS)          v = ((const float4*)Wq)[j];
            else if (j < 2 * W_CHUNKS) v = ((const float4*)Wk)[j - W_CHUNKS];
            else                       v = ((const float4*)Wv)[j - 2 * W_CHUNKS];
            optr = (ushort4*)dst + i4;
        } else {
            v = ((const float4*)Wo)[j - 3 * W_CHUNKS];
            optr = (ushort4*)WoB + (j - 3 * W_CHUNKS);
        }
    }
    ushort4 o;
    o.x = f2bf(v.x); o.y = f2bf(v.y); o.z = f2bf(v.z); o.w = f2bf(v.w);
    *optr = o;
}

// ---------------------------------------------------------------------------
// Kernel 1: QKV projection, 128x128 tile, BK=64, global_load_lds + XOR swizzle.
// Q written pre-scaled by C2.  Q,K -> [b][h][s][d];  V -> [b][h][d][s].
// ---------------------------------------------------------------------------
__global__ __launch_bounds__(256) void qkv_gemm(
    const unsigned short* __restrict__ Hb,   // [8192][768] bf16
    const unsigned short* __restrict__ Wb,   // [2304][768] bf16 (Wq|Wk|Wv)
    unsigned short* __restrict__ qkv) {
    __shared__ __align__(16) unsigned short Ah[128 * 64];
    __shared__ __align__(16) unsigned short Bh[128 * 64];
    const int t = threadIdx.x, w = t >> 6, lane = t & 63;
    const int quad = lane >> 4, r16 = lane & 15;
    const int wm = w >> 1, wn = w & 1;
    const int m0 = blockIdx.y * 128, n0g = blockIdx.x * 128;
    const int wsel = n0g / ED, n0 = n0g % ED;
    const int lrow = lane >> 3;
    const int lchs = ((lane & 7) ^ (lrow & 7)) * 8;   // swizzled source chunk

    f32x4 acc[4][4] = {};
    for (int kt = 0; kt < ED / 64; ++kt) {
        const int k0 = kt * 64;
#pragma unroll
        for (int i = 0; i < 4; ++i) {
            int row = i * 32 + w * 8;
            cp16(&Hb[(size_t)(m0 + row + lrow) * ED + k0 + lchs], &Ah[row * 64]);
            cp16(&Wb[(size_t)(n0g + row + lrow) * ED + k0 + lchs], &Bh[row * 64]);
        }
        __syncthreads();
#pragma unroll
        for (int kk = 0; kk < 2; ++kk) {
            bf16x8 aF[4], bF[4];
#pragma unroll
            for (int mi = 0; mi < 4; ++mi) {
                int R = wm * 64 + mi * 16 + r16;
                aF[mi] = *(const bf16x8*)&Ah[R * 64 + (((kk * 4 + quad) ^ (r16 & 7)) * 8)];
            }
#pragma unroll
            for (int ni = 0; ni < 4; ++ni) {
                int R = wn * 64 + ni * 16 + r16;
                bF[ni] = *(const bf16x8*)&Bh[R * 64 + (((kk * 4 + quad) ^ (r16 & 7)) * 8)];
            }
            if (wsel == 2) {   // V: compute C^T so V^T stores stay coalesced
#pragma unroll
                for (int mi = 0; mi < 4; ++mi)
#pragma unroll
                    for (int ni = 0; ni < 4; ++ni)
                        acc[mi][ni] = __builtin_amdgcn_mfma_f32_16x16x32_bf16(
                            bF[ni], aF[mi], acc[mi][ni], 0, 0, 0);
            } else {
#pragma unroll
                for (int mi = 0; mi < 4; ++mi)
#pragma unroll
                    for (int ni = 0; ni < 4; ++ni)
                        acc[mi][ni] = __builtin_amdgcn_mfma_f32_16x16x32_bf16(
                            aF[mi], bF[ni], acc[mi][ni], 0, 0, 0);
            }
        }
        __syncthreads();
    }
    const size_t WSZ = (size_t)BHT * SEQ * HD;
    if (wsel == 2) {
#pragma unroll
        for (int mi = 0; mi < 4; ++mi)
#pragma unroll
            for (int ni = 0; ni < 4; ++ni)
#pragma unroll
                for (int r = 0; r < 4; ++r) {
                    int m  = m0 + wm * 64 + mi * 16 + r16;
                    int nn = n0 + wn * 64 + ni * 16 + quad * 4 + r;
                    int b = m >> 12, s = m & 4095;
                    int hh = nn >> 6, dd = nn & 63;
                    qkv[2 * WSZ + (((size_t)b * NH + hh) * HD + dd) * SEQ + s] =
                        f2bf(acc[mi][ni][r]);
                }
    } else {
        const float sc = (wsel == 0) ? C2 : 1.0f;
#pragma unroll
        for (int mi = 0; mi < 4; ++mi)
#pragma unroll
            for (int ni = 0; ni < 4; ++ni)
#pragma unroll
                for (int r = 0; r < 4; ++r) {
                    int m = m0 + wm * 64 + mi * 16 + quad * 4 + r;
                    int b = m >> 12, s = m & 4095;
                    int nn = n0 + wn * 64 + ni * 16 + r16;
                    int hh = nn >> 6, dd = nn & 63;
                    size_t off = (((size_t)b * NH + hh) * SEQ + s) * HD + dd;
                    qkv[(size_t)wsel * WSZ + off] = f2bf(acc[mi][ni][r] * sc);
                }
    }
}

// ---------------------------------------------------------------------------
// Kernel 2: flash attention, 32x32x16 MFMA, fixed-max softmax, Q pre-scaled.
// Round-8 = r1 compute body (best verified, 148.6us) + r5's counted-vmcnt
// sync skeleton (correctness-proven) AT FULL OCCUPANCY:
//  - Mall LDS table DELETED: mask comes from global (coalesced L2-hit),
//    prefetched one tile ahead into 2 regs. LDS = 3-slot K (24KB) +
//    2-slot V (16KB) = 40KB -> 3 blocks/CU (r5's 48KB gave only 2 -> two
//    scheduling generations; that, not the pipeline, caused r5's loss).
//  - per iter: issue mask(t+1) loads, then cp16 K(t+2),V(t+1); QK(t);
//    `s_waitcnt vmcnt(4); s_barrier` (drains K(t+1),V(t),mask — issued a
//    full tile earlier); PV(t); plain s_barrier (WAR). vmcnt never 0 in
//    the main loop. Peeled t=62 (vmcnt(2)), t=63 (vmcnt(0)).
//  - denominator: r1's VALU row-sums + final shfl (measured best).
// Spill tripwire: WRITE_SIZE must stay ~12.3MB (r7's spills showed 27.6).
// ---------------------------------------------------------------------------
#define QK_PACK(KOFF, M0, M1, PF) do {                                         \
    float p_[2][16];                                                           \
    float rs0 = 0.f, rs1 = 0.f, rs2 = 0.f, rs3 = 0.f;                          \
_Pragma("unroll")                                                              \
    for (int st = 0; st < 2; ++st) {                                           \
        bf16x8 am = {};                                                        \
        if (hi == 0) am[0] = (short)f2bf(LOG2E * (st ? (M1) : (M0)));          \
        f32x16 sA = {};                                                        \
        sA = __builtin_amdgcn_mfma_f32_32x32x16_bf16(am, bOnes, sA, 0, 0, 0);  \
        __builtin_amdgcn_s_setprio(1);                                         \
_Pragma("unroll")                                                              \
        for (int kc = 0; kc < 4; ++kc) {                                       \
            bf16x8 kF = *(const bf16x8*)                                       \
                &Ksm[(KOFF) + (st * 32 + n31) * 64 + (((2 * kc + hi) ^ sw) * 8)]; \
            sA = __builtin_amdgcn_mfma_f32_32x32x16_bf16(kF, qF[kc], sA, 0, 0, 0); \
        }                                                                      \
        __builtin_amdgcn_s_setprio(0);                                         \
_Pragma("unroll")                                                              \
        for (int r = 0; r < 16; ++r) p_[st][r] = __builtin_amdgcn_exp2f(sA[r]); \
        rs0 += p_[st][0] + p_[st][4] + p_[st][8]  + p_[st][12];                \
        rs1 += p_[st][1] + p_[st][5] + p_[st][9]  + p_[st][13];                \
        rs2 += p_[st][2] + p_[st][6] + p_[st][10] + p_[st][14];                \
        rs3 += p_[st][3] + p_[st][7] + p_[st][11] + p_[st][15];                \
    }                                                                          \
    l_i += (rs0 + rs1) + (rs2 + rs3);                                          \
_Pragma("unroll")                                                              \
    for (int st = 0; st < 2; ++st) {                                           \
        uint32_t pw[8];                                                        \
_Pragma("unroll")                                                              \
        for (int i = 0; i < 8; ++i)                                            \
            pw[i] = cvtpk(p_[st][2 * i], p_[st][2 * i + 1]);                   \
_Pragma("unroll")                                                              \
        for (int hf = 0; hf < 2; ++hf) {                                       \
            auto r02 = __builtin_amdgcn_permlane32_swap(                       \
                pw[hf * 4 + 0], pw[hf * 4 + 2], false, false);                 \
            auto r13 = __builtin_amdgcn_permlane32_swap(                       \
                pw[hf * 4 + 1], pw[hf * 4 + 3], false, false);                 \
            union { u32x4 u; bf16x8 h; } f_;                                   \
            f_.u[0] = r02[0]; f_.u[1] = r13[0]; f_.u[2] = r02[1]; f_.u[3] = r13[1]; \
            PF[st * 2 + hf] = f_.h;                                            \
        }                                                                      \
    }                                                                          \
} while (0)

#define PV_ACC(VOFF, PF) do {                                                  \
    __builtin_amdgcn_s_setprio(1);                                             \
_Pragma("unroll")                                                              \
    for (int kc = 0; kc < 4; ++kc) {                                           \
_Pragma("unroll")                                                              \
        for (int dt = 0; dt < 2; ++dt) {                                       \
            bf16x8 vF = *(const bf16x8*)                                       \
                &Vtsm[(VOFF) + (dt * 32 + n31) * 64 + (((2 * kc + hi) ^ sw) * 8)]; \
            oAcc[dt] = __builtin_amdgcn_mfma_f32_32x32x16_bf16(                \
                vF, PF[kc], oAcc[dt], 0, 0, 0);                                \
        }                                                                      \
    }                                                                          \
    __builtin_amdgcn_s_setprio(0);                                             \
} while (0)

__global__ __launch_bounds__(256) void flash_attn(
    const unsigned short* __restrict__ qkv, const float* __restrict__ mask,
    unsigned short* __restrict__ ctx) {
    __shared__ __align__(16) unsigned short Ksm[3 * 4096];   // 3-slot [key][dim], swizzled, 24KB
    __shared__ __align__(16) unsigned short Vtsm[2 * 4096];  // 2-slot [dim][key], swizzled, 16KB
    const int t  = threadIdx.x;
    const int bh = blockIdx.y;
    const int b  = bh / NH;
    const int h  = bh % NH;
    const int qbase = blockIdx.x * 128;
    const size_t WSZ = (size_t)BHT * SEQ * HD;
    const unsigned short* Qp = qkv + (size_t)bh * SEQ * HD;
    const unsigned short* Kp = Qp + WSZ;
    const unsigned short* Vt = qkv + 2 * WSZ + (size_t)bh * HD * SEQ;
    const int w = t >> 6, lane = t & 63, n31 = lane & 31, hi = lane >> 5;
    const int lrow = lane >> 3;
    const int lchs = ((lane & 7) ^ (lrow & 7)) * 8;

    bf16x8 qF[4];
    {
        int qrow = qbase + w * 32 + n31;
#pragma unroll
        for (int kc = 0; kc < 4; ++kc)
            qF[kc] = *(const bf16x8*)&Qp[(size_t)qrow * HD + kc * 16 + hi * 8];
    }
    bf16x8 bOnes = {};
    if (hi == 0) bOnes[0] = (short)0x3F80;   // 1.0 at k==0

    // mask for this batch row, read straight from global (L2-hit, coalesced);
    // per tile each lane needs mask[kt*64 + st*32 + n31] only.
    const float* mrow = mask + (size_t)b * SEQ;
    float mReg0 = mrow[n31], mReg1 = mrow[32 + n31];   // tile 0

    const int row0 = w * 16, row1 = w * 16 + 8;   // this wave's staging rows

    // prologue: K(0)->slot0, K(1)->slot1, V(0)->vslot0; one full drain
    cp16(&Kp[(size_t)(row0 + lrow) * HD + lchs],      &Ksm[row0 * 64]);
    cp16(&Kp[(size_t)(row1 + lrow) * HD + lchs],      &Ksm[row1 * 64]);
    cp16(&Kp[(size_t)(64 + row0 + lrow) * HD + lchs], &Ksm[4096 + row0 * 64]);
    cp16(&Kp[(size_t)(64 + row1 + lrow) * HD + lchs], &Ksm[4096 + row1 * 64]);
    cp16(&Vt[(size_t)(row0 + lrow) * SEQ + lchs],     &Vtsm[row0 * 64]);
    cp16(&Vt[(size_t)(row1 + lrow) * SEQ + lchs],     &Vtsm[row1 * 64]);
    __syncthreads();

    f32x16 oAcc[2] = {};
    float l_i = 0.0f;
    const int sw = n31 & 7;                  // row-swizzle for frag reads
    int kCur = 0, kNxt = 4096, kFar = 8192;  // rotating K slots (ushort offsets)
    int vCur = 0;                            // V slot (0 / 4096)

    for (int kt = 0; kt < 62; ++kt) {
        // prefetch next tile's mask regs FIRST (older than the cp16s below,
        // so the mid-iter vmcnt(4) also guarantees they've landed)
        float mN0 = mrow[(kt + 1) * 64 + n31];
        float mN1 = mrow[(kt + 1) * 64 + 32 + n31];
        // issue prefetch: K(kt+2) -> kFar, V(kt+1) -> other V slot
        cp16(&Kp[(size_t)((kt + 2) * 64 + row0 + lrow) * HD + lchs], &Ksm[kFar + row0 * 64]);
        cp16(&Kp[(size_t)((kt + 2) * 64 + row1 + lrow) * HD + lchs], &Ksm[kFar + row1 * 64]);
        cp16(&Vt[(size_t)(row0 + lrow) * SEQ + (kt + 1) * 64 + lchs], &Vtsm[(vCur ^ 4096) + row0 * 64]);
        cp16(&Vt[(size_t)(row1 + lrow) * SEQ + (kt + 1) * 64 + lchs], &Vtsm[(vCur ^ 4096) + row1 * 64]);

        bf16x8 pF[4];
        QK_PACK(kCur, mReg0, mReg1, pF);
        // drains K(kt+1), V(kt), mask(kt+1); leaves the 4 just-issued cp16
        asm volatile("s_waitcnt vmcnt(4)\n\ts_barrier" ::: "memory");
        PV_ACC(vCur, pF);
        asm volatile("s_barrier" ::: "memory");   // WAR: V slot reuse next iter

        int tmp = kCur; kCur = kNxt; kNxt = kFar; kFar = tmp;
        vCur ^= 4096;
        mReg0 = mN0; mReg1 = mN1;
    }
    // kt = 62: no K prefetch (t+2 = 64); V(63) + mask(63) only
    {
        float mN0 = mrow[63 * 64 + n31];
        float mN1 = mrow[63 * 64 + 32 + n31];
        cp16(&Vt[(size_t)(row0 + lrow) * SEQ + 63 * 64 + lchs], &Vtsm[(vCur ^ 4096) + row0 * 64]);
        cp16(&Vt[(size_t)(row1 + lrow) * SEQ + 63 * 64 + lchs], &Vtsm[(vCur ^ 4096) + row1 * 64]);
        bf16x8 pF[4];
        QK_PACK(kCur, mReg0, mReg1, pF);
        asm volatile("s_waitcnt vmcnt(2)\n\ts_barrier" ::: "memory");  // drains K(63), V(62), mask(63)
        PV_ACC(vCur, pF);
        asm volatile("s_barrier" ::: "memory");
        int tmp = kCur; kCur = kNxt; kNxt = kFar; kFar = tmp;
        vCur ^= 4096;
        mReg0 = mN0; mReg1 = mN1;
    }
    // kt = 63
    {
        bf16x8 pF[4];
        QK_PACK(kCur, mReg0, mReg1, pF);
        asm volatile("s_waitcnt vmcnt(0)\n\ts_barrier" ::: "memory");  // drains V(63)
        PV_ACC(vCur, pF);
    }

    l_i += __shfl_xor(l_i, 32);
    float inv = 1.0f / l_i;
    int s = qbase + w * 32 + n31;
    unsigned short* obase = &ctx[((size_t)b * SEQ + s) * ED + h * HD];
#pragma unroll
    for (int dt = 0; dt < 2; ++dt)
#pragma unroll
        for (int g = 0; g < 4; ++g) {
            ushort4 o;
            o.x = f2bf(oAcc[dt][4 * g + 0] * inv);
            o.y = f2bf(oAcc[dt][4 * g + 1] * inv);
            o.z = f2bf(oAcc[dt][4 * g + 2] * inv);
            o.w = f2bf(oAcc[dt][4 * g + 3] * inv);
            *(ushort4*)&obase[dt * 32 + hi * 4 + 8 * g] = o;
        }
}

// ---------------------------------------------------------------------------
// Kernel 3: output projection, 128x128 tile m97-style.
// out[m][n] = sum_k ctx[m][k]*Wo[n][k] + bo[n], fp32 output.
// ---------------------------------------------------------------------------
__global__ __launch_bounds__(256) void out_gemm(
    const unsigned short* __restrict__ Ab,   // ctx bf16 [8192][768]
    const unsigned short* __restrict__ Wob,  // [768][768] bf16
    const float* __restrict__ bo, float* __restrict__ out) {
    __shared__ __align__(16) unsigned short Ah[128 * 64];
    __shared__ __align__(16) unsigned short Bh[128 * 64];
    const int t = threadIdx.x, w = t >> 6, lane = t & 63;
    const int quad = lane >> 4, r16 = lane & 15;
    const int wm = w >> 1, wn = w & 1;
    const int m0 = blockIdx.y * 128, n0 = blockIdx.x * 128;
    const int lrow = lane >> 3;
    const int lchs = ((lane & 7) ^ (lrow & 7)) * 8;

    f32x4 acc[4][4] = {};
    for (int kt = 0; kt < ED / 64; ++kt) {
        const int k0 = kt * 64;
#pragma unroll
        for (int i = 0; i < 4; ++i) {
            int row = i * 32 + w * 8;
            cp16(&Ab[(size_t)(m0 + row + lrow) * ED + k0 + lchs], &Ah[row * 64]);
            cp16(&Wob[(size_t)(n0 + row + lrow) * ED + k0 + lchs], &Bh[row * 64]);
        }
        __syncthreads();
#pragma unroll
        for (int kk = 0; kk < 2; ++kk) {
            bf16x8 aF[4], bF[4];
#pragma unroll
            for (int mi = 0; mi < 4; ++mi) {
                int R = wm * 64 + mi * 16 + r16;
                aF[mi] = *(const bf16x8*)&Ah[R * 64 + (((kk * 4 + quad) ^ (r16 & 7)) * 8)];
            }
#pragma unroll
            for (int ni = 0; ni < 4; ++ni) {
                int R = wn * 64 + ni * 16 + r16;
                bF[ni] = *(const bf16x8*)&Bh[R * 64 + (((kk * 4 + quad) ^ (r16 & 7)) * 8)];
            }
#pragma unroll
            for (int mi = 0; mi < 4; ++mi)
#pragma unroll
                for (int ni = 0; ni < 4; ++ni)
                    acc[mi][ni] = __builtin_amdgcn_mfma_f32_16x16x32_bf16(
                        aF[mi], bF[ni], acc[mi][ni], 0, 0, 0);
        }
        __syncthreads();
    }
    float bov[4];
#pragma unroll
    for (int ni = 0; ni < 4; ++ni) bov[ni] = bo[n0 + wn * 64 + ni * 16 + r16];
#pragma unroll
    for (int mi = 0; mi < 4; ++mi)
#pragma unroll
        for (int ni = 0; ni < 4; ++ni)
#pragma unroll
            for (int r = 0; r < 4; ++r) {
                int m = m0 + wm * 64 + mi * 16 + quad * 4 + r;
                int n = n0 + wn * 64 + ni * 16 + r16;
                out[(size_t)m * ED + n] = acc[mi][ni][r] + bov[ni];
            }
}

// ---------------------------------------------------------------------------
extern "C" void kernel_launch(void* const* d_in, const int* in_sizes, int n_in,
                              void* d_out, int out_size, void* d_ws, size_t ws_size,
                              hipStream_t stream) {
    const float* H    = (const float*)d_in[0];
    const float* mask = (const float*)d_in[1];
    const float* Wq   = (const float*)d_in[2];
    const float* Wk   = (const float*)d_in[3];
    const float* Wv   = (const float*)d_in[4];
    const float* Wo   = (const float*)d_in[5];
    const float* bo   = (const float*)d_in[6];
    unsigned short* ws = (unsigned short*)d_ws;
    const size_t WSZ = (size_t)BHT * SEQ * HD;
    unsigned short* qkv = ws;                           // 3*WSZ bf16
    unsigned short* ctx = ws + 3 * WSZ;                 // [8192][768] bf16
    unsigned short* WoB = ctx + (size_t)MTOT * ED;      // [768][768] bf16
    float* out = (float*)d_out;
    // d_out doubles as scratch for bf16 H and Wqkv until out_gemm overwrites it
    unsigned short* Hb = (unsigned short*)d_out;        // 6291456 elems
    unsigned short* Wb = Hb + (size_t)MTOT * ED;        // 1769472 elems

    convert_bf16<<<CVT_TOTAL / 256, 256, 0, stream>>>(H, Wq, Wk, Wv, Wo, Hb, WoB);
    qkv_gemm<<<dim3(3 * ED / 128, MTOT / 128), 256, 0, stream>>>(Hb, Wb, qkv);
    flash_attn<<<dim3(SEQ / 128, BHT), 256, 0, stream>>>(qkv, mask, ctx);
    out_gemm<<<dim3(ED / 128, MTOT / 128), 256, 0, stream>>>(ctx, WoB, bo, out);
}